// Round 4
// baseline (354.001 us; speedup 1.0000x reference)
//
#include <hip/hip_runtime.h>

// SudokuLoss: B=65536 puzzles, G=9, C=10 classes, BS=3.
// v5: masked logits GATHER (v3's memory pattern) + atomic-free two-phase
// LDS aggregation (v4's structure). History:
//   v3 (gather + 30 LDS atomics/cell)  = 128.6us  -> LDS-atomic-RMW bound
//   v4 (dense stream + no atomics)     = ~94us    -> 40B-strided loads touch
//       40 lines/wave-load (5x L1 amplification), 80KB/CU hot footprint
//       thrashes 32KB L1 -> replays through L2; HBM floor alone was 40us.
// v5 reads ONLY masked cells (~10% -> ~29% of lines): HBM ~88MB = 14us
// floor; gather touches ~10 lines/load (fits L1); LDS has zero atomics
// (phase 1: private 48B slot/cell; phase 2: conflict-free b128 group
// reads -- stride-12 lane pattern covers all 32 banks exactly once).
// Per-cell math identical to v4 (absmax 0.0): skipped cells write exact 0s.

constexpr int kB    = 65536;
constexpr int PPB   = 6;            // puzzles per block
constexpr int TPB   = 512;          // threads per block (8 waves)
constexpr int NSLOT = 256;          // global accumulation slots
constexpr int SLOT_STRIDE = 16;     // floats per slot (64B = one cache line)
constexpr int CSTRIDE = 12;         // floats per cell slot in LDS (48B, 16B-aligned)

__global__ __launch_bounds__(TPB) void sudoku_main(
    const float* __restrict__ logits,
    const int*   __restrict__ targets,
    const int*   __restrict__ puzzles,
    float*       __restrict__ ws)   // ws: [NSLOT][16]; per slot: [0]=diff2 [1]=ce [2]=mcnt
{
    // per-cell slots: [0]=mask, [1..9]=masked softmax probs (classes 1..9)
    __shared__ __align__(16) float probs[TPB * CSTRIDE];   // 24576 B
    __shared__ float red[3][TPB / 64];

    const int tid    = threadIdx.x;
    const int pzbase = blockIdx.x * PPB;
    const int q      = tid / 81;               // puzzle within block (0..6)

    float ce = 0.f, mcnt = 0.f;
    float wv[10];
    #pragma unroll
    for (int c = 0; c < 10; ++c) wv[c] = 0.f;

    const bool active = (q < PPB) && (pzbase + q < kB);
    if (active) {
        const int idx = pzbase * 81 + tid;     // == (pzbase+q)*81 + ci
        const int pz = puzzles[idx];           // coalesced, unit-stride

        if (pz == 0) {                         // ~10% of lanes
            // exec-masked gathers: target (4B) + 5x float2 (40B cell),
            // all independent -> issued together, ~10 lines/wave-load
            const int tg = targets[idx];
            const float* xp = logits + (size_t)idx * 10;
            float2 v0 = *(const float2*)(xp + 0);
            float2 v1 = *(const float2*)(xp + 2);
            float2 v2 = *(const float2*)(xp + 4);
            float2 v3 = *(const float2*)(xp + 6);
            float2 v4 = *(const float2*)(xp + 8);
            float x[10];
            x[0]=v0.x; x[1]=v0.y; x[2]=v1.x; x[3]=v1.y; x[4]=v2.x;
            x[5]=v2.y; x[6]=v3.x; x[7]=v3.y; x[8]=v4.x; x[9]=v4.y;

            float mx = x[0];
            #pragma unroll
            for (int c = 1; c < 10; ++c) mx = fmaxf(mx, x[c]);
            float e[10];
            float S = 0.f;
            #pragma unroll
            for (int c = 0; c < 10; ++c) { e[c] = __expf(x[c] - mx); S += e[c]; }
            const float inv = 1.0f / S;

            float xt = x[0];
            #pragma unroll
            for (int c = 1; c < 10; ++c) xt = (tg == c) ? x[c] : xt;
            ce   = mx + __logf(S) - xt;        // -log_softmax(x)[tg]
            mcnt = 1.f;
            wv[0] = 1.f;
            #pragma unroll
            for (int c = 1; c < 10; ++c) wv[c] = e[c] * inv;
        }
    }
    // every thread (incl. inactive/unmasked) writes its slot: zeros there.
    // stride-12 b128 lane pattern: banks 12l..12l+3 mod 32 -> conflict-free.
    {
        float* dst = &probs[tid * CSTRIDE];
        *(float4*)(dst + 0) = make_float4(wv[0], wv[1], wv[2], wv[3]);
        *(float4*)(dst + 4) = make_float4(wv[4], wv[5], wv[6], wv[7]);
        *(float2*)(dst + 8) = make_float2(wv[8], wv[9]);
    }
    __syncthreads();

    // phase 2: one thread per (puzzle, group); group-major for wave uniformity
    //   t in [0,54)    : rows  (q2 = t/9,       r = t%9)
    //   t in [54,108)  : cols  (q2 = (t-54)/9,  j = (t-54)%9)
    //   t in [108,162) : boxes (q2 = (t-108)/9, b = (t-108)%9)
    float diff2 = 0.f;
    if (tid < PPB * 27) {
        float s[10];
        #pragma unroll
        for (int c = 0; c < 10; ++c) s[c] = 0.f;

        if (tid < PPB * 9) {
            const int q2 = tid / 9, r = tid - q2 * 9;
            const float* base = &probs[(q2 * 81 + r * 9) * CSTRIDE];
            #pragma unroll
            for (int i = 0; i < 9; ++i) {
                const float* cell = base + i * CSTRIDE;
                const float4 a = *(const float4*)(cell + 0);
                const float4 b = *(const float4*)(cell + 4);
                const float2 c2 = *(const float2*)(cell + 8);
                s[0]+=a.x; s[1]+=a.y; s[2]+=a.z; s[3]+=a.w;
                s[4]+=b.x; s[5]+=b.y; s[6]+=b.z; s[7]+=b.w;
                s[8]+=c2.x; s[9]+=c2.y;
            }
        } else if (tid < PPB * 18) {
            const int u = tid - PPB * 9;
            const int q2 = u / 9, j = u - q2 * 9;
            const float* base = &probs[(q2 * 81 + j) * CSTRIDE];
            #pragma unroll
            for (int i = 0; i < 9; ++i) {
                const float* cell = base + i * (9 * CSTRIDE);
                const float4 a = *(const float4*)(cell + 0);
                const float4 b = *(const float4*)(cell + 4);
                const float2 c2 = *(const float2*)(cell + 8);
                s[0]+=a.x; s[1]+=a.y; s[2]+=a.z; s[3]+=a.w;
                s[4]+=b.x; s[5]+=b.y; s[6]+=b.z; s[7]+=b.w;
                s[8]+=c2.x; s[9]+=c2.y;
            }
        } else {
            const int u = tid - PPB * 18;
            const int q2 = u / 9, b = u - q2 * 9;
            const int br = b / 3, bc = b - br * 3;
            const float* base = &probs[(q2 * 81 + br * 27 + bc * 3) * CSTRIDE];
            #pragma unroll
            for (int dr = 0; dr < 3; ++dr) {
                #pragma unroll
                for (int dc = 0; dc < 3; ++dc) {
                    const float* cell = base + (dr * 9 + dc) * CSTRIDE;
                    const float4 a = *(const float4*)(cell + 0);
                    const float4 bb = *(const float4*)(cell + 4);
                    const float2 c2 = *(const float2*)(cell + 8);
                    s[0]+=a.x; s[1]+=a.y; s[2]+=a.z; s[3]+=a.w;
                    s[4]+=bb.x; s[5]+=bb.y; s[6]+=bb.z; s[7]+=bb.w;
                    s[8]+=c2.x; s[9]+=c2.y;
                }
            }
        }
        const float tm = s[0] * (1.f / 9.f);
        #pragma unroll
        for (int c = 1; c < 10; ++c) { const float d = s[c] - tm; diff2 += d * d; }
    }

    // wave (64-lane) reduction, then cross-wave via LDS
    #pragma unroll
    for (int off = 32; off > 0; off >>= 1) {
        diff2 += __shfl_down(diff2, off);
        ce    += __shfl_down(ce, off);
        mcnt  += __shfl_down(mcnt, off);
    }
    const int wave = tid >> 6;
    if ((tid & 63) == 0) { red[0][wave] = diff2; red[1][wave] = ce; red[2][wave] = mcnt; }
    __syncthreads();
    if (tid == 0) {
        float d = 0.f, c2 = 0.f, m = 0.f;
        #pragma unroll
        for (int w = 0; w < TPB / 64; ++w) { d += red[0][w]; c2 += red[1][w]; m += red[2][w]; }
        float* slot = ws + (size_t)(blockIdx.x & (NSLOT - 1)) * SLOT_STRIDE;
        atomicAdd(&slot[0], d);
        atomicAdd(&slot[1], c2);
        atomicAdd(&slot[2], m);
    }
}

__global__ void sudoku_final(const float* __restrict__ ws, float* __restrict__ out)
{
    // one wave: each lane sums 4 slots, then shuffle-reduce
    const int t = threadIdx.x;
    float d = 0.f, c2 = 0.f, m = 0.f;
    for (int s = t; s < NSLOT; s += 64) {
        const float* sl = ws + (size_t)s * SLOT_STRIDE;
        d += sl[0]; c2 += sl[1]; m += sl[2];
    }
    #pragma unroll
    for (int off = 32; off > 0; off >>= 1) {
        d  += __shfl_down(d, off);
        c2 += __shfl_down(c2, off);
        m  += __shfl_down(m, off);
    }
    if (t == 0) {
        const float ce_loss = c2 / (m + 1e-8f);
        // each of row/col/box loss = sum(diff^2)/(B*9); constraint = sum/27
        const float constraint = d / ((float)kB * 9.f * 27.f);
        out[0] = ce_loss + 0.1f * constraint;
        out[1] = ce_loss;
        out[2] = constraint;
    }
}

extern "C" void kernel_launch(void* const* d_in, const int* in_sizes, int n_in,
                              void* d_out, int out_size, void* d_ws, size_t ws_size,
                              hipStream_t stream)
{
    const float* logits  = (const float*)d_in[0];
    const int*   targets = (const int*)d_in[1];
    const int*   puzzles = (const int*)d_in[2];
    float* ws  = (float*)d_ws;
    float* out = (float*)d_out;

    hipMemsetAsync(d_ws, 0, NSLOT * SLOT_STRIDE * sizeof(float), stream);

    const int blocks = (kB + PPB - 1) / PPB;   // 10923
    sudoku_main<<<blocks, TPB, 0, stream>>>(logits, targets, puzzles, ws);
    sudoku_final<<<1, 64, 0, stream>>>(ws, out);
}

// Round 5
// 295.653 us; speedup vs baseline: 1.1974x; 1.1974x over previous
//
#include <hip/hip_runtime.h>

// SudokuLoss: B=65536 puzzles, G=9, C=10 classes, BS=3.
// v6: PERSISTENT GRID. History of main-kernel times (bench - ~238us fixed
// harness fills): v1=89us (1024 blocks, serial 27-cell threads),
// v3=128.6 (10923 blocks, LDS atomics), v4=114 (dense, no atomics),
// v5=116 (gather, no atomics).
// Post-mortem of v4~=v5: memory pattern irrelevant, atomics only -15us,
// bottom-up pipe accounting sums to ~40us yet v2-v5 all floor at ~110-115us
// = 10923 WGs x ~10.4ns: a workgroup dispatch/retire-rate floor (also
// explains v2's 59.7% occupancy with all pipes <8% busy).
// v6: 1024 blocks = 4/CU x 256 CU fully co-resident (LDS 24.7KB x 4 = 99KB,
// launch_bounds(512,8) caps VGPRs at 64 for 8 waves/SIMD). Each block loops
// 11 rounds x 6 puzzles over the same LDS buffer; next round's puzzle values
// prefetched to registers; wave-reduce + global atomics once per block.
// Per-cell math identical to v4/v5 (absmax 0.0).

constexpr int kB     = 65536;
constexpr int TPB    = 512;          // threads per block (8 waves)
constexpr int NBLK   = 1024;         // 4 blocks/CU x 256 CU: fully resident
constexpr int PPBLK  = kB / NBLK;    // 64 puzzles per block
constexpr int PPB_R  = 6;            // puzzles per round (486 cells < 512)
constexpr int ROUNDS = (PPBLK + PPB_R - 1) / PPB_R;   // 11 (last round: 4)
constexpr int NSLOT  = 256;          // global accumulation slots
constexpr int SLOT_STRIDE = 16;      // floats per slot (64B line)
constexpr int CSTRIDE = 12;          // floats per cell slot in LDS (48B)

__global__ __launch_bounds__(TPB, 8) void sudoku_main(
    const float* __restrict__ logits,
    const int*   __restrict__ targets,
    const int*   __restrict__ puzzles,
    float*       __restrict__ ws)   // ws: [NSLOT][16]; [0]=diff2 [1]=ce [2]=mcnt
{
    // per-cell slots: [0]=mask, [1..9]=masked softmax probs (classes 1..9)
    __shared__ __align__(16) float probs[TPB * CSTRIDE];   // 24576 B
    __shared__ float red[3][TPB / 64];

    const int  tid  = threadIdx.x;
    const int  q    = tid / 81;              // puzzle-in-round (0..6; 6=idle)
    const bool actq = (q < PPB_R);
    const size_t blkbase = (size_t)blockIdx.x * PPBLK * 81;

    float ce = 0.f, mcnt = 0.f, diff2 = 0.f;

    // round-0 puzzle value
    int pz_cur = 1;
    if (actq) pz_cur = puzzles[blkbase + tid];

    for (int r = 0; r < ROUNDS; ++r) {
        // prefetch next round's puzzle value: issued a full round (~2-4K cyc)
        // before use, so the pz load never sits on the critical chain
        int pz_next = 1;
        if (r + 1 < ROUNDS) {
            const bool actn = actq && ((r + 1) * PPB_R + q < PPBLK);
            if (actn) pz_next = puzzles[blkbase + (size_t)(r + 1) * (PPB_R * 81) + tid];
        }

        const bool act = actq && (r * PPB_R + q < PPBLK);
        float wv[10];
        #pragma unroll
        for (int c = 0; c < 10; ++c) wv[c] = 0.f;

        if (act && pz_cur == 0) {            // ~10% of lanes
            const size_t idx = blkbase + (size_t)r * (PPB_R * 81) + tid;
            const int tg = targets[idx];
            const float* xp = logits + idx * 10;
            float2 v0 = *(const float2*)(xp + 0);
            float2 v1 = *(const float2*)(xp + 2);
            float2 v2 = *(const float2*)(xp + 4);
            float2 v3 = *(const float2*)(xp + 6);
            float2 v4 = *(const float2*)(xp + 8);
            float x[10];
            x[0]=v0.x; x[1]=v0.y; x[2]=v1.x; x[3]=v1.y; x[4]=v2.x;
            x[5]=v2.y; x[6]=v3.x; x[7]=v3.y; x[8]=v4.x; x[9]=v4.y;

            float mx = x[0];
            #pragma unroll
            for (int c = 1; c < 10; ++c) mx = fmaxf(mx, x[c]);
            float e[10];
            float S = 0.f;
            #pragma unroll
            for (int c = 0; c < 10; ++c) { e[c] = __expf(x[c] - mx); S += e[c]; }
            const float inv = 1.0f / S;

            float xt = x[0];
            #pragma unroll
            for (int c = 1; c < 10; ++c) xt = (tg == c) ? x[c] : xt;
            ce   += mx + __logf(S) - xt;     // -log_softmax(x)[tg]
            mcnt += 1.f;
            wv[0] = 1.f;
            #pragma unroll
            for (int c = 1; c < 10; ++c) wv[c] = e[c] * inv;
        }

        // all 512 threads write their slot (zeros where unmasked/inactive):
        // stride-12 b128 pattern spreads across all 32 banks
        {
            float* dst = &probs[tid * CSTRIDE];
            *(float4*)(dst + 0) = make_float4(wv[0], wv[1], wv[2], wv[3]);
            *(float4*)(dst + 4) = make_float4(wv[4], wv[5], wv[6], wv[7]);
            *(float2*)(dst + 8) = make_float2(wv[8], wv[9]);
        }
        __syncthreads();

        // phase 2: one thread per (puzzle, group), group-major.
        // inactive puzzles' slots are all-zero -> contribute 0 to diff2.
        if (tid < PPB_R * 27) {
            float s[10];
            #pragma unroll
            for (int c = 0; c < 10; ++c) s[c] = 0.f;

            if (tid < PPB_R * 9) {                       // rows
                const int q2 = tid / 9, rr = tid - q2 * 9;
                const float* base = &probs[(q2 * 81 + rr * 9) * CSTRIDE];
                #pragma unroll
                for (int i = 0; i < 9; ++i) {
                    const float* cell = base + i * CSTRIDE;
                    const float4 a = *(const float4*)(cell + 0);
                    const float4 b = *(const float4*)(cell + 4);
                    const float2 c2 = *(const float2*)(cell + 8);
                    s[0]+=a.x; s[1]+=a.y; s[2]+=a.z; s[3]+=a.w;
                    s[4]+=b.x; s[5]+=b.y; s[6]+=b.z; s[7]+=b.w;
                    s[8]+=c2.x; s[9]+=c2.y;
                }
            } else if (tid < PPB_R * 18) {               // cols
                const int u = tid - PPB_R * 9;
                const int q2 = u / 9, j = u - q2 * 9;
                const float* base = &probs[(q2 * 81 + j) * CSTRIDE];
                #pragma unroll
                for (int i = 0; i < 9; ++i) {
                    const float* cell = base + i * (9 * CSTRIDE);
                    const float4 a = *(const float4*)(cell + 0);
                    const float4 b = *(const float4*)(cell + 4);
                    const float2 c2 = *(const float2*)(cell + 8);
                    s[0]+=a.x; s[1]+=a.y; s[2]+=a.z; s[3]+=a.w;
                    s[4]+=b.x; s[5]+=b.y; s[6]+=b.z; s[7]+=b.w;
                    s[8]+=c2.x; s[9]+=c2.y;
                }
            } else {                                     // boxes
                const int u = tid - PPB_R * 18;
                const int q2 = u / 9, b = u - q2 * 9;
                const int br = b / 3, bc = b - br * 3;
                const float* base = &probs[(q2 * 81 + br * 27 + bc * 3) * CSTRIDE];
                #pragma unroll
                for (int dr = 0; dr < 3; ++dr) {
                    #pragma unroll
                    for (int dc = 0; dc < 3; ++dc) {
                        const float* cell = base + (dr * 9 + dc) * CSTRIDE;
                        const float4 a = *(const float4*)(cell + 0);
                        const float4 bb = *(const float4*)(cell + 4);
                        const float2 c2 = *(const float2*)(cell + 8);
                        s[0]+=a.x; s[1]+=a.y; s[2]+=a.z; s[3]+=a.w;
                        s[4]+=bb.x; s[5]+=bb.y; s[6]+=bb.z; s[7]+=bb.w;
                        s[8]+=c2.x; s[9]+=c2.y;
                    }
                }
            }
            const float tm = s[0] * (1.f / 9.f);
            #pragma unroll
            for (int c = 1; c < 10; ++c) { const float d = s[c] - tm; diff2 += d * d; }
        }
        __syncthreads();   // protect probs before next round's writes

        pz_cur = pz_next;
    }

    // once per block: wave (64-lane) reduction, then cross-wave via LDS
    #pragma unroll
    for (int off = 32; off > 0; off >>= 1) {
        diff2 += __shfl_down(diff2, off);
        ce    += __shfl_down(ce, off);
        mcnt  += __shfl_down(mcnt, off);
    }
    const int wave = tid >> 6;
    if ((tid & 63) == 0) { red[0][wave] = diff2; red[1][wave] = ce; red[2][wave] = mcnt; }
    __syncthreads();
    if (tid == 0) {
        float d = 0.f, c2 = 0.f, m = 0.f;
        #pragma unroll
        for (int w = 0; w < TPB / 64; ++w) { d += red[0][w]; c2 += red[1][w]; m += red[2][w]; }
        float* slot = ws + (size_t)(blockIdx.x & (NSLOT - 1)) * SLOT_STRIDE;
        atomicAdd(&slot[0], d);
        atomicAdd(&slot[1], c2);
        atomicAdd(&slot[2], m);
    }
}

__global__ void sudoku_final(const float* __restrict__ ws, float* __restrict__ out)
{
    // one wave: each lane sums 4 slots, then shuffle-reduce
    const int t = threadIdx.x;
    float d = 0.f, c2 = 0.f, m = 0.f;
    for (int s = t; s < NSLOT; s += 64) {
        const float* sl = ws + (size_t)s * SLOT_STRIDE;
        d += sl[0]; c2 += sl[1]; m += sl[2];
    }
    #pragma unroll
    for (int off = 32; off > 0; off >>= 1) {
        d  += __shfl_down(d, off);
        c2 += __shfl_down(c2, off);
        m  += __shfl_down(m, off);
    }
    if (t == 0) {
        const float ce_loss = c2 / (m + 1e-8f);
        // each of row/col/box loss = sum(diff^2)/(B*9); constraint = sum/27
        const float constraint = d / ((float)kB * 9.f * 27.f);
        out[0] = ce_loss + 0.1f * constraint;
        out[1] = ce_loss;
        out[2] = constraint;
    }
}

extern "C" void kernel_launch(void* const* d_in, const int* in_sizes, int n_in,
                              void* d_out, int out_size, void* d_ws, size_t ws_size,
                              hipStream_t stream)
{
    const float* logits  = (const float*)d_in[0];
    const int*   targets = (const int*)d_in[1];
    const int*   puzzles = (const int*)d_in[2];
    float* ws  = (float*)d_ws;
    float* out = (float*)d_out;

    hipMemsetAsync(d_ws, 0, NSLOT * SLOT_STRIDE * sizeof(float), stream);

    sudoku_main<<<NBLK, TPB, 0, stream>>>(logits, targets, puzzles, ws);
    sudoku_final<<<1, 64, 0, stream>>>(ws, out);
}